// Round 1
// baseline (295.119 us; speedup 1.0000x reference)
//
#include <hip/hip_runtime.h>
#include <hip/hip_bf16.h>

typedef __bf16 bf16x8 __attribute__((ext_vector_type(8)));
typedef float f32x4 __attribute__((ext_vector_type(4)));

#define NQ     10
#define M_ROWS 16384
#define N_COLS 1024
#define K_DIM  4096

// ---------------------------------------------------------------- helpers
__device__ __forceinline__ void gload_lds16(const __hip_bfloat16* g, __hip_bfloat16* l) {
  __builtin_amdgcn_global_load_lds(
      (const __attribute__((address_space(1))) void*)g,
      (__attribute__((address_space(3))) void*)l,
      16, 0, 0);
}

// ---------------------------------------------------------------- prep kernels
// W1 (4096 x 10) -> W1T (10 x 4096), fp32
__global__ void __launch_bounds__(256) tr_w1(const float* __restrict__ W1,
                                             float* __restrict__ W1T) {
  int f = blockIdx.x * 256 + threadIdx.x;   // 16 blocks -> 4096
#pragma unroll
  for (int j = 0; j < NQ; j++)
    W1T[j * K_DIM + f] = W1[f * NQ + j];
}

// W2 (1024 x 4096) fp32 -> bf16
__global__ void __launch_bounds__(256) cvt_w2(const float* __restrict__ in,
                                              __hip_bfloat16* __restrict__ out) {
  int i = (blockIdx.x * 256 + threadIdx.x) * 4;   // 4096 blocks -> 4194304 elems
  float4 v = *(const float4*)(in + i);
  union { __hip_bfloat16 h[4]; uint2 u; } p;
  p.h[0] = __float2bfloat16(v.x);
  p.h[1] = __float2bfloat16(v.y);
  p.h[2] = __float2bfloat16(v.z);
  p.h[3] = __float2bfloat16(v.w);
  *(uint2*)(out + i) = p.u;
}

// ---------------------------------------------------------------- h = relu(q_out @ W1^T) in bf16
// closed-form q_out: q[0] = prod_{j=1..9} cos(theta_j); q[k] = prod_{j=0..k} cos(theta_j)
__global__ void __launch_bounds__(256) compute_h(const float* __restrict__ x,
                                                 const float* __restrict__ qp,
                                                 const float* __restrict__ W1T,
                                                 __hip_bfloat16* __restrict__ h) {
  __shared__ float qs[8][NQ];
  const int tid = threadIdx.x;
  const int r0 = blockIdx.x * 8;   // 2048 blocks x 8 rows

  if (tid < 8 * NQ) {
    int r = tid / NQ, j = tid % NQ;
    qs[r][j] = cosf(x[(r0 + r) * NQ + j] + qp[j]);
  }
  __syncthreads();
  if (tid < 8) {
    float c[NQ];
#pragma unroll
    for (int j = 0; j < NQ; j++) c[j] = qs[tid][j];
    float pref = c[0];
    float prod19 = 1.f;
#pragma unroll
    for (int j = 1; j < NQ; j++) prod19 *= c[j];
    qs[tid][0] = prod19;
#pragma unroll
    for (int k = 1; k < NQ; k++) { pref *= c[k]; qs[tid][k] = pref; }
  }
  __syncthreads();

  float q[8][NQ];
#pragma unroll
  for (int r = 0; r < 8; r++)
#pragma unroll
    for (int j = 0; j < NQ; j++) q[r][j] = qs[r][j];   // LDS broadcast reads

#pragma unroll 1
  for (int k = 0; k < 16; k++) {
    int f = (k << 8) + tid;        // 16*256 = 4096 features
    float w[NQ];
#pragma unroll
    for (int j = 0; j < NQ; j++) w[j] = W1T[j * K_DIM + f];   // coalesced, L2-resident
#pragma unroll
    for (int r = 0; r < 8; r++) {
      float acc = 0.f;
#pragma unroll
      for (int j = 0; j < NQ; j++) acc = fmaf(q[r][j], w[j], acc);
      h[(r0 + r) * K_DIM + f] = __float2bfloat16(fmaxf(acc, 0.f));
    }
  }
}

// ---------------------------------------------------------------- C = A(MxK) * B(NxK)^T, bf16 in fp32 out
// m97 structure: 128x128 tile, BK=64, global_load_lds x16, 16x16x32 bf16 MFMA
__global__ void __launch_bounds__(256) gemm_bt(const __hip_bfloat16* __restrict__ A,
                                               const __hip_bfloat16* __restrict__ B,
                                               float* __restrict__ C) {
  __shared__ __align__(16) __hip_bfloat16 As[128 * 64];
  __shared__ __align__(16) __hip_bfloat16 Bs[128 * 64];

  const int tid  = threadIdx.x;
  const int wave = tid >> 6;
  const int lane = tid & 63;
  const int lm   = lane & 15;
  const int quad = lane >> 4;
  const int wm   = (wave & 1) * 64;
  const int wn   = (wave >> 1) * 64;
  const int col0 = blockIdx.x * 128;   // N fastest: A-tile reused across all 8 bn
  const int row0 = blockIdx.y * 128;

  const int ldr = wave * 8 + (lane >> 3);   // 0..31: row within 32-row issue group
  const int ldc = (lane & 7) * 8;           // 0..56: col (bf16 elems)

  f32x4 acc[4][4];
#pragma unroll
  for (int i = 0; i < 4; i++)
#pragma unroll
    for (int j = 0; j < 4; j++) acc[i][j] = (f32x4){0.f, 0.f, 0.f, 0.f};

  for (int k0 = 0; k0 < K_DIM; k0 += 64) {
    // stage A,B tiles: 128 rows x 64 cols bf16, lane-contiguous (no padding — required)
#pragma unroll
    for (int i = 0; i < 4; i++) {
      int r = i * 32 + ldr;
      gload_lds16(A + (row0 + r) * K_DIM + k0 + ldc, As + (i * 32 + wave * 8) * 64);
      gload_lds16(B + (col0 + r) * K_DIM + k0 + ldc, Bs + (i * 32 + wave * 8) * 64);
    }
    __syncthreads();

#pragma unroll
    for (int kk = 0; kk < 64; kk += 32) {
      bf16x8 af[4], bb[4];
#pragma unroll
      for (int mf = 0; mf < 4; mf++)
        af[mf] = *(const bf16x8*)(As + (wm + mf * 16 + lm) * 64 + kk + quad * 8);
#pragma unroll
      for (int nf = 0; nf < 4; nf++)
        bb[nf] = *(const bf16x8*)(Bs + (wn + nf * 16 + lm) * 64 + kk + quad * 8);
#pragma unroll
      for (int mf = 0; mf < 4; mf++)
#pragma unroll
        for (int nf = 0; nf < 4; nf++)
          acc[mf][nf] = __builtin_amdgcn_mfma_f32_16x16x32_bf16(af[mf], bb[nf], acc[mf][nf], 0, 0, 0);
    }
    __syncthreads();
  }

  // epilogue: C/D layout col = lane&15, row = quad*4 + reg
#pragma unroll
  for (int mf = 0; mf < 4; mf++) {
#pragma unroll
    for (int nf = 0; nf < 4; nf++) {
      int row = row0 + wm + mf * 16 + quad * 4;
      int col = col0 + wn + nf * 16 + lm;
#pragma unroll
      for (int r = 0; r < 4; r++)
        C[(row + r) * N_COLS + col] = acc[mf][nf][r];
    }
  }
}

// ---------------------------------------------------------------- launch
extern "C" void kernel_launch(void* const* d_in, const int* in_sizes, int n_in,
                              void* d_out, int out_size, void* d_ws, size_t ws_size,
                              hipStream_t stream) {
  const float* x  = (const float*)d_in[0];   // 32*512*10
  const float* qp = (const float*)d_in[1];   // 10
  const float* W1 = (const float*)d_in[2];   // 4096*10
  const float* W2 = (const float*)d_in[3];   // 1024*4096
  float* out = (float*)d_out;                // 32*512*1024 fp32

  char* ws = (char*)d_ws;
  float*          W1T = (float*)ws;                                   // 163840 B
  __hip_bfloat16* W2b = (__hip_bfloat16*)(ws + 163840);               // 8388608 B
  __hip_bfloat16* hbf = (__hip_bfloat16*)(ws + 163840 + 8388608);     // 134217728 B

  tr_w1<<<16, 256, 0, stream>>>(W1, W1T);
  cvt_w2<<<4096, 256, 0, stream>>>(W2, W2b);
  compute_h<<<M_ROWS / 8, 256, 0, stream>>>(x, qp, W1T, hbf);
  gemm_bt<<<dim3(N_COLS / 128, M_ROWS / 128), 256, 0, stream>>>(hbf, W2b, out);
}

// Round 2
// 273.736 us; speedup vs baseline: 1.0781x; 1.0781x over previous
//
#include <hip/hip_runtime.h>
#include <hip/hip_bf16.h>

typedef __bf16 bf16x8 __attribute__((ext_vector_type(8)));
typedef float f32x4 __attribute__((ext_vector_type(4)));

#define NQ     10
#define M_ROWS 16384
#define N_COLS 1024
#define K_DIM  4096

// ---------------------------------------------------------------- helpers
__device__ __forceinline__ void gload_lds16(const __hip_bfloat16* g, __hip_bfloat16* l) {
  __builtin_amdgcn_global_load_lds(
      (const __attribute__((address_space(1))) void*)g,
      (__attribute__((address_space(3))) void*)l,
      16, 0, 0);
}

// ---------------------------------------------------------------- W2 fp32 -> bf16
__global__ void __launch_bounds__(256) cvt_w2(const float* __restrict__ in,
                                              __hip_bfloat16* __restrict__ out) {
  int i = (blockIdx.x * 256 + threadIdx.x) * 4;
  float4 v = *(const float4*)(in + i);
  union { __hip_bfloat16 h[4]; uint2 u; } p;
  p.h[0] = __float2bfloat16(v.x);
  p.h[1] = __float2bfloat16(v.y);
  p.h[2] = __float2bfloat16(v.z);
  p.h[3] = __float2bfloat16(v.w);
  *(uint2*)(out + i) = p.u;
}

// ---------------------------------------------------------------- h = relu(q_out @ W1^T) bf16
// closed form: q[0] = prod_{j=1..9} cos(theta_j); q[k] = prod_{j=0..k} cos(theta_j)
// 8 rows/block; each thread covers 8 consecutive cols -> bf16x8 16B stores.
__global__ void __launch_bounds__(256) compute_h(const float* __restrict__ x,
                                                 const float* __restrict__ qp,
                                                 const float* __restrict__ W1,
                                                 __hip_bfloat16* __restrict__ h) {
  __shared__ float qs[8][NQ];
  const int tid = threadIdx.x;
  const int r0 = blockIdx.x * 8;

  if (tid < 8 * NQ) {
    int r = tid / NQ, j = tid % NQ;
    qs[r][j] = cosf(x[(r0 + r) * NQ + j] + qp[j]);
  }
  __syncthreads();
  if (tid < 8) {
    float c[NQ];
#pragma unroll
    for (int j = 0; j < NQ; j++) c[j] = qs[tid][j];
    float pref = c[0];
    float prod19 = 1.f;
#pragma unroll
    for (int j = 1; j < NQ; j++) prod19 *= c[j];
    qs[tid][0] = prod19;
#pragma unroll
    for (int k = 1; k < NQ; k++) { pref *= c[k]; qs[tid][k] = pref; }
  }
  __syncthreads();

#pragma unroll 1
  for (int k = 0; k < 2; k++) {
    const int col0 = k * 2048 + tid * 8;
    // W1 is (4096 x 10) row-major: rows col0..col0+7 are 80 contiguous floats
    float w[8][NQ];
    const float* wp = W1 + col0 * NQ;
#pragma unroll
    for (int c = 0; c < 8; c++)
#pragma unroll
      for (int j = 0; j < NQ; j++) w[c][j] = wp[c * NQ + j];

#pragma unroll
    for (int r = 0; r < 8; r++) {
      float q[NQ];
#pragma unroll
      for (int j = 0; j < NQ; j++) q[j] = qs[r][j];   // broadcast reads
      union { __hip_bfloat16 hh[8]; uint4 u; } pk;
#pragma unroll
      for (int c = 0; c < 8; c++) {
        float acc = 0.f;
#pragma unroll
        for (int j = 0; j < NQ; j++) acc = fmaf(q[j], w[c][j], acc);
        pk.hh[c] = __float2bfloat16(fmaxf(acc, 0.f));
      }
      *(uint4*)(h + (r0 + r) * K_DIM + col0) = pk.u;
    }
  }
}

// ---------------------------------------------------------------- C = A(MxK) * B(NxK)^T, bf16 in fp32 out
// m97 structure + XOR bank-conflict swizzle + XCD-aware block decode.
__global__ void __launch_bounds__(256) gemm_bt(const __hip_bfloat16* __restrict__ A,
                                               const __hip_bfloat16* __restrict__ B,
                                               float* __restrict__ C) {
  __shared__ __align__(16) __hip_bfloat16 As[128 * 64];
  __shared__ __align__(16) __hip_bfloat16 Bs[128 * 64];

  const int tid  = threadIdx.x;
  const int wave = tid >> 6;
  const int lane = tid & 63;
  const int lm   = lane & 15;
  const int quad = lane >> 4;
  const int wm   = (wave & 1) * 64;
  const int wn   = (wave >> 1) * 64;

  // XCD-aware decode: blocks round-robin L%8 across XCDs. XCD d owns
  // row-tiles [16d, 16d+16) x all 8 col-tiles -> per-XCD k-step working set
  // ~384 KB (L2-resident); A fetched from HBM once.
  const int L    = blockIdx.x;
  const int xcd  = L & 7;
  const int idx  = L >> 3;
  const int col0 = (idx & 7) * 128;
  const int row0 = ((xcd << 4) | (idx >> 3)) * 128;

  const int ldr = wave * 8 + (lane >> 3);                 // row within 32-row group
  const int ldc = (((lane & 7) ^ (lane >> 3)) << 3);      // XOR-swizzled col chunk
  // LDS[R][p] = global[R][p ^ (R & 7)]  (R&7 == lane>>3 at staging,
  //                                      R&7 == lm&7 at read time)

  f32x4 acc[4][4];
#pragma unroll
  for (int i = 0; i < 4; i++)
#pragma unroll
    for (int j = 0; j < 4; j++) acc[i][j] = (f32x4){0.f, 0.f, 0.f, 0.f};

  for (int k0 = 0; k0 < K_DIM; k0 += 64) {
#pragma unroll
    for (int i = 0; i < 4; i++) {
      int r = i * 32 + ldr;
      gload_lds16(A + (row0 + r) * K_DIM + k0 + ldc, As + (i * 32 + wave * 8) * 64);
      gload_lds16(B + (col0 + r) * K_DIM + k0 + ldc, Bs + (i * 32 + wave * 8) * 64);
    }
    __syncthreads();

#pragma unroll
    for (int kk = 0; kk < 64; kk += 32) {
      bf16x8 af[4], bb[4];
#pragma unroll
      for (int mf = 0; mf < 4; mf++) {
        int R = wm + mf * 16 + lm;
        af[mf] = *(const bf16x8*)(As + R * 64 + ((((kk >> 3) + quad) ^ (lm & 7)) << 3));
      }
#pragma unroll
      for (int nf = 0; nf < 4; nf++) {
        int R = wn + nf * 16 + lm;
        bb[nf] = *(const bf16x8*)(Bs + R * 64 + ((((kk >> 3) + quad) ^ (lm & 7)) << 3));
      }
#pragma unroll
      for (int mf = 0; mf < 4; mf++)
#pragma unroll
        for (int nf = 0; nf < 4; nf++)
          acc[mf][nf] = __builtin_amdgcn_mfma_f32_16x16x32_bf16(af[mf], bb[nf], acc[mf][nf], 0, 0, 0);
    }
    __syncthreads();
  }

  // epilogue: C/D layout col = lane&15, row = quad*4 + reg
#pragma unroll
  for (int mf = 0; mf < 4; mf++) {
#pragma unroll
    for (int nf = 0; nf < 4; nf++) {
      int row = row0 + wm + mf * 16 + quad * 4;
      int col = col0 + wn + nf * 16 + lm;
#pragma unroll
      for (int r = 0; r < 4; r++)
        C[(row + r) * N_COLS + col] = acc[mf][nf][r];
    }
  }
}

// ---------------------------------------------------------------- launch
extern "C" void kernel_launch(void* const* d_in, const int* in_sizes, int n_in,
                              void* d_out, int out_size, void* d_ws, size_t ws_size,
                              hipStream_t stream) {
  const float* x  = (const float*)d_in[0];   // 32*512*10
  const float* qp = (const float*)d_in[1];   // 10
  const float* W1 = (const float*)d_in[2];   // 4096*10
  const float* W2 = (const float*)d_in[3];   // 1024*4096
  float* out = (float*)d_out;                // 32*512*1024 fp32

  char* ws = (char*)d_ws;
  __hip_bfloat16* W2b = (__hip_bfloat16*)ws;                // 8388608 B
  __hip_bfloat16* hbf = (__hip_bfloat16*)(ws + 8388608);    // 134217728 B

  cvt_w2<<<4096, 256, 0, stream>>>(W2, W2b);
  compute_h<<<M_ROWS / 8, 256, 0, stream>>>(x, qp, W1, hbf);
  gemm_bt<<<(N_COLS / 128) * (M_ROWS / 128), 256, 0, stream>>>(hbf, W2b, out);
}